// Round 21
// baseline (370.039 us; speedup 1.0000x reference)
//
#include <hip/hip_runtime.h>
#include <hip/hip_bf16.h>

typedef unsigned short u16;
typedef __attribute__((ext_vector_type(8))) short bf16x8;
typedef __attribute__((ext_vector_type(4))) float f32x4;
typedef __attribute__((ext_vector_type(2))) unsigned uint2v;

#define MFMA16(a, b, c) __builtin_amdgcn_mfma_f32_16x16x32_bf16(a, b, c, 0, 0, 0)

__device__ __forceinline__ u16 f2bf(float f) {
  union { float f; unsigned u; } v; v.f = f;
  unsigned r = v.u + 0x7fffu + ((v.u >> 16) & 1u);
  return (u16)(r >> 16);
}

// Pack two f32 -> packed bf16 pair (lo in bits 0..15). Pure C++ (no inline asm).
__device__ __forceinline__ unsigned pkbf(float lo, float hi) {
  union { __hip_bfloat162 h; unsigned u; } v;
  v.h = __hip_bfloat162(__float2bfloat16(lo), __float2bfloat16(hi));
  return v.u;
}

// In-register transpose, permlane edition (r14-verified, bit-identical results):
// input a0/a1 = M[t*16+g*4+r][li] (f32, C-layout of a 32x16 block, t=0,1);
// output frag: lane holds bf16 M[g*8+j][li] — MFMA operand fragment for M^T.
__device__ __forceinline__ bf16x8 xform(f32x4 a0, f32x4 a1) {
  unsigned p0 = pkbf(a0[0], a0[1]), p1 = pkbf(a0[2], a0[3]);
  unsigned p2 = pkbf(a1[0], a1[1]), p3 = pkbf(a1[2], a1[3]);
  uint2v s02 = __builtin_amdgcn_permlane32_swap(p0, p2, false, false);
  uint2v w02 = __builtin_amdgcn_permlane16_swap(s02.x, s02.y, false, false);
  uint2v s13 = __builtin_amdgcn_permlane32_swap(p1, p3, false, false);
  uint2v w13 = __builtin_amdgcn_permlane16_swap(s13.x, s13.y, false, false);
  union { bf16x8 v; unsigned w[4]; } o;
  o.w[0] = w02.x; o.w[1] = w13.x; o.w[2] = w02.y; o.w[3] = w13.y;
  return o.v;
}

// xor-16 / xor-32 lane reductions via permlane-swap (VALU; r14-verified).
__device__ __forceinline__ float pmax16(float v) {
  union { float f; unsigned u; } a; a.f = v;
  uint2v r = __builtin_amdgcn_permlane16_swap(a.u, a.u, false, false);
  union { unsigned u; float f; } x, y; x.u = r.x; y.u = r.y;
  return fmaxf(x.f, y.f);
}
__device__ __forceinline__ float pmax32(float v) {
  union { float f; unsigned u; } a; a.f = v;
  uint2v r = __builtin_amdgcn_permlane32_swap(a.u, a.u, false, false);
  union { unsigned u; float f; } x, y; x.u = r.x; y.u = r.y;
  return fmaxf(x.f, y.f);
}
__device__ __forceinline__ float psum16(float v) {
  union { float f; unsigned u; } a; a.f = v;
  uint2v r = __builtin_amdgcn_permlane16_swap(a.u, a.u, false, false);
  union { unsigned u; float f; } x, y; x.u = r.x; y.u = r.y;
  return x.f + y.f;
}
__device__ __forceinline__ float psum32(float v) {
  union { float f; unsigned u; } a; a.f = v;
  uint2v r = __builtin_amdgcn_permlane32_swap(a.u, a.u, false, false);
  union { unsigned u; float f; } x, y; x.u = r.x; y.u = r.y;
  return x.f + y.f;
}

// ---------------- pack: weights -> bf16 fragment layout, bias -> per-lane frag order ----
__global__ void pack_kernel(const float* __restrict__ wqkv_w,
                            const float* __restrict__ wp_w,
                            const float* __restrict__ bias_table,
                            u16* __restrict__ wpack, u16* __restrict__ wppack,
                            float* __restrict__ biasf) {
  int i = blockIdx.x * 256 + threadIdx.x;
  if (i < 110592) {
    int j = i & 7, l = (i >> 3) & 63;
    int rest = i >> 9;
    int ks = rest % 6, nt = rest / 6;
    int k = ks * 32 + (l >> 4) * 8 + j;
    int n = nt * 16 + (l & 15);
    wpack[i] = f2bf(wqkv_w[k * 576 + n]);
  } else if (i < 147456) {
    int i2 = i - 110592;
    int j = i2 & 7, l = (i2 >> 3) & 63;
    int rest = i2 >> 9;
    int ks = rest % 6, nt = rest / 6;
    int k = ks * 32 + (l >> 4) * 8 + j;
    int n = nt * 16 + (l & 15);
    wppack[i2] = f2bf(wp_w[k * 192 + n]);
  } else if (i < 172032) {
    int i2 = i - 147456;            // 0..24575
    int r = i2 & 3, lane = (i2 >> 2) & 63, mt = (i2 >> 8) & 3, nt = (i2 >> 10) & 3, h = i2 >> 12;
    int q = nt * 16 + (lane & 15);
    int kk = mt * 16 + (lane >> 4) * 4 + r;
    int idx = ((q >> 3) - (kk >> 3) + 7) * 15 + ((q & 7) - (kk & 7) + 7);
    biasf[i2] = bias_table[idx * 6 + h];
  }
}

// ---------------- attn: 1 block = 2 WAVES = 2 HEADS of one window (r20 body). ---------
// r21 experiment (single variable): (128,3) -> 170-reg/wave cap -> 3 waves/SIMD.
// r20 was register-limited to 2 waves/SIMD (22% occ) with the LDS limit unused.
// This 1-head straight-line body measures 108 arch VGPR; the ~25-reg overflow
// past the (128,3) arch cap should land in AGPRs (1-cyc accvgpr; qt/kt/va are
// natural accumulator candidates), NOT scratch — unlike r4/r7/r11 whose fat
// multi-head bodies (~150+ arch) overflowed both. TRIPWIRE: WRITE >= 150 MB
// means scratch spill -> revert to r20's (128,2).
__global__ __launch_bounds__(128, 3) void attn6(
    const float* __restrict__ x, const u16* __restrict__ wpack,
    const float* __restrict__ wqkv_b, const float* __restrict__ biasf,
    u16* __restrict__ y) {
  __shared__ u16 xs[12288];                   // [4 mt][6 ks][64 lane][8] bf16
  const int lane = threadIdx.x & 63;
  const int wv = threadIdx.x >> 6;            // 0,1
  // chunked bijective XCD swizzle: 13824 blocks = 8 XCDs x 1728.
  const int fid = (blockIdx.x & 7) * 1728 + (blockIdx.x >> 3);
  const int w = fid / 3, sub = fid - w * 3;   // window, head-pair
  const int h = sub * 2 + wv;                 // this wave's head
  const int bb = w / 576, rem = w - bb * 576;
  const int wy = rem / 24, wx = rem - (rem / 24) * 24;
  const size_t xbase = (size_t)bb * 36864;
  const int g = lane >> 4, li = lane & 15;

  // per-lane pixel for token (mt*16 + li): pix(mt) = pix0 + mt*384
  const int pix0 = (wy * 8 + (li >> 3)) * 192 + wx * 8 + (li & 7);
  const float* xr = x + (xbase + pix0) * 192 + g * 8;
  const u16* wbase = wpack + lane * 8;

  const float scale = 0.17677669529663687f;   // 1/sqrt(32)
  const f32x4 zero4 = {0.f, 0.f, 0.f, 0.f};

  // ---- stage x -> LDS fragments ONCE (2 waves split 24 chunks: 12 each) ----
#pragma unroll
  for (int ci = 0; ci < 12; ++ci) {
    const int c = wv * 12 + ci, mt = c / 6, ks = c - (c / 6) * 6;
    const float* p = xr + mt * 73728 + ks * 32;   // +mt*384 pixels
    float4 f0 = *(const float4*)p;
    float4 f1 = *(const float4*)(p + 4);
    union { bf16x8 v; unsigned u[4]; } o;
    o.u[0] = pkbf(f0.x, f0.y); o.u[1] = pkbf(f0.z, f0.w);
    o.u[2] = pkbf(f1.x, f1.y); o.u[3] = pkbf(f1.z, f1.w);
    *(bf16x8*)(xs + ((mt * 6 + ks) * 64 + lane) * 8) = o.v;
  }
  __syncthreads();

  // ---- pass Q: Q^T = mfma(Wq, x_lds)  (32-reg accumulator block) ----
  bf16x8 qf[4];
  {
    f32x4 qt[2][4];
#pragma unroll
    for (int i = 0; i < 2; ++i)
#pragma unroll
      for (int mt = 0; mt < 4; ++mt) qt[i][mt] = zero4;
#pragma unroll
    for (int ks = 0; ks < 6; ++ks) {
      bf16x8 af[4];
#pragma unroll
      for (int mt = 0; mt < 4; ++mt)
        af[mt] = *(const bf16x8*)(xs + ((mt * 6 + ks) * 64 + lane) * 8);
#pragma unroll
      for (int i = 0; i < 2; ++i) {
        bf16x8 wq = *(const bf16x8*)(wbase + ((2 * h + i) * 6 + ks) * 512);
#pragma unroll
        for (int mt = 0; mt < 4; ++mt) qt[i][mt] = MFMA16(wq, af[mt], qt[i][mt]);
      }
    }
    f32x4 bq0 = *(const f32x4*)(wqkv_b + h * 32 + g * 4);
    f32x4 bq1 = *(const f32x4*)(wqkv_b + h * 32 + 16 + g * 4);
#pragma unroll
    for (int mt = 0; mt < 4; ++mt)
      qf[mt] = xform((qt[0][mt] + bq0) * scale, (qt[1][mt] + bq1) * scale);
  }

  // ---- pass K: K^T = mfma(Wk, x_lds)  (32-reg accumulator block) ----
  bf16x8 kf[4];
  {
    f32x4 kt[2][4];
#pragma unroll
    for (int i = 0; i < 2; ++i)
#pragma unroll
      for (int mt = 0; mt < 4; ++mt) kt[i][mt] = zero4;
#pragma unroll
    for (int ks = 0; ks < 6; ++ks) {
      bf16x8 af[4];
#pragma unroll
      for (int mt = 0; mt < 4; ++mt)
        af[mt] = *(const bf16x8*)(xs + ((mt * 6 + ks) * 64 + lane) * 8);
#pragma unroll
      for (int i = 0; i < 2; ++i) {
        bf16x8 wk = *(const bf16x8*)(wbase + ((12 + 2 * h + i) * 6 + ks) * 512);
#pragma unroll
        for (int mt = 0; mt < 4; ++mt) kt[i][mt] = MFMA16(wk, af[mt], kt[i][mt]);
      }
    }
    f32x4 bk0 = *(const f32x4*)(wqkv_b + 192 + h * 32 + g * 4);
    f32x4 bk1 = *(const f32x4*)(wqkv_b + 192 + h * 32 + 16 + g * 4);
#pragma unroll
    for (int mt = 0; mt < 4; ++mt)
      kf[mt] = xform(kt[0][mt] + bk0, kt[1][mt] + bk1);
  }

  // ---- pass V: V = mfma(x_lds, Wv)  (32-reg accumulator block) ----
  bf16x8 vf[2][2];    // [d-tile i][key-chunk ks2] — V^T A-operand
  {
    f32x4 va[4][2];
#pragma unroll
    for (int mt = 0; mt < 4; ++mt) { va[mt][0] = zero4; va[mt][1] = zero4; }
#pragma unroll
    for (int ks = 0; ks < 6; ++ks) {
      bf16x8 af[4];
#pragma unroll
      for (int mt = 0; mt < 4; ++mt)
        af[mt] = *(const bf16x8*)(xs + ((mt * 6 + ks) * 64 + lane) * 8);
      bf16x8 wv0 = *(const bf16x8*)(wbase + ((24 + 2 * h) * 6 + ks) * 512);
      bf16x8 wv1 = *(const bf16x8*)(wbase + ((25 + 2 * h) * 6 + ks) * 512);
#pragma unroll
      for (int mt = 0; mt < 4; ++mt) {
        va[mt][0] = MFMA16(af[mt], wv0, va[mt][0]);
        va[mt][1] = MFMA16(af[mt], wv1, va[mt][1]);
      }
    }
    float bva0 = wqkv_b[384 + h * 32 + li], bva1 = wqkv_b[384 + h * 32 + 16 + li];
#pragma unroll
    for (int i = 0; i < 2; ++i) {
      float bv = i ? bva1 : bva0;
#pragma unroll
      for (int ks2 = 0; ks2 < 2; ++ks2)
        vf[i][ks2] = xform(va[ks2 * 2][i] + bv, va[ks2 * 2 + 1][i] + bv);
    }
  }

  // ---- per-q-tile: S^T = mfma(K,Q,bias), softmax, P-frag, PV, fused store ----
  const float* bfh = biasf + h * 4096 + lane * 4;
  u16* yp = y + (size_t)h * 9437184 + (xbase + pix0) * 32 + g * 8;
#pragma unroll
  for (int nt = 0; nt < 4; ++nt) {
    f32x4 em[4];
#pragma unroll
    for (int mt = 0; mt < 4; ++mt) {
      f32x4 bias_c = *(const f32x4*)(bfh + (nt * 4 + mt) * 256);
      em[mt] = MFMA16(kf[mt], qf[nt], bias_c);   // bias folded into C-operand
    }
    float mx = -1e30f;
#pragma unroll
    for (int mt = 0; mt < 4; ++mt)
      mx = fmaxf(mx, fmaxf(fmaxf(em[mt][0], em[mt][1]), fmaxf(em[mt][2], em[mt][3])));
    mx = pmax16(mx);
    mx = pmax32(mx);
    float s = 0.f;
#pragma unroll
    for (int mt = 0; mt < 4; ++mt)
#pragma unroll
      for (int r = 0; r < 4; ++r) { em[mt][r] = __expf(em[mt][r] - mx); s += em[mt][r]; }
    s = psum16(s);
    s = psum32(s);
    float inv = 1.0f / s;
    f32x4 y0 = zero4, y1 = zero4;   // this q-tile's output only
#pragma unroll
    for (int ks2 = 0; ks2 < 2; ++ks2) {
      bf16x8 pf = xform(em[ks2 * 2] * inv, em[ks2 * 2 + 1] * inv);
      y0 = MFMA16(vf[0][ks2], pf, y0);
      y1 = MFMA16(vf[1][ks2], pf, y1);
    }
    // Y^T -> y-fragment; store HEAD-MAJOR y'[h][b*36864 + pix][32]
    bf16x8 yfr = xform(y0, y1);
    *(bf16x8*)(yp + nt * 12288) = yfr;   // +nt*384 pixels * 32 ch
  }
}

// ---------------- projection GEMM: out = y' @ wp + b (head-major y reads) ----------
__global__ __launch_bounds__(256, 2) void proj_kernel(
    const u16* __restrict__ y, const u16* __restrict__ wppack,
    const float* __restrict__ wp_b, float* __restrict__ out) {
  const int tid = threadIdx.x;
  const int lane = tid & 63, wv = tid >> 6;
  const int g = lane >> 4, li = lane & 15;
  const size_t row0 = (size_t)blockIdx.x * 128 + wv * 32;
  const f32x4 zero4 = {0.f, 0.f, 0.f, 0.f};
  f32x4 acc[2][12];
#pragma unroll
  for (int mt = 0; mt < 2; ++mt)
#pragma unroll
    for (int nt = 0; nt < 12; ++nt) acc[mt][nt] = zero4;
#pragma unroll
  for (int ks = 0; ks < 6; ++ks) {
    bf16x8 af[2];
#pragma unroll
    for (int mt = 0; mt < 2; ++mt)
      af[mt] = *(const bf16x8*)(y + (size_t)ks * 9437184 + (row0 + mt * 16 + li) * 32 + g * 8);
#pragma unroll
    for (int nt = 0; nt < 12; ++nt) {
      bf16x8 bf = *(const bf16x8*)(wppack + (nt * 6 + ks) * 512 + lane * 8);
      acc[0][nt] = MFMA16(af[0], bf, acc[0][nt]);
      acc[1][nt] = MFMA16(af[1], bf, acc[1][nt]);
    }
  }
#pragma unroll
  for (int nt = 0; nt < 12; ++nt) {
    float bb = wp_b[nt * 16 + li];
#pragma unroll
    for (int mt = 0; mt < 2; ++mt)
#pragma unroll
      for (int r = 0; r < 4; ++r)
        out[(row0 + mt * 16 + g * 4 + r) * 192 + nt * 16 + li] = acc[mt][nt][r] + bb;
  }
}

extern "C" void kernel_launch(void* const* d_in, const int* in_sizes, int n_in,
                              void* d_out, int out_size, void* d_ws, size_t ws_size,
                              hipStream_t stream) {
  (void)in_sizes; (void)n_in; (void)out_size; (void)ws_size;
  const float* x          = (const float*)d_in[0];
  const float* wqkv_w     = (const float*)d_in[1];
  const float* wqkv_b     = (const float*)d_in[2];
  const float* wp_w       = (const float*)d_in[3];
  const float* wp_b       = (const float*)d_in[4];
  const float* bias_table = (const float*)d_in[5];
  float* out = (float*)d_out;
  char* ws = (char*)d_ws;
  u16* wpack   = (u16*)(ws);              // 221184 B
  u16* wppack  = (u16*)(ws + 221184);     //  73728 B
  float* biasf = (float*)(ws + 294912);   //  98304 B
  u16* y       = (u16*)(ws + 393216);     // 113246208 B (head-major: [6][294912][32])

  pack_kernel<<<672, 256, 0, stream>>>(wqkv_w, wp_w, bias_table, wpack, wppack, biasf);
  attn6<<<13824, 128, 0, stream>>>(x, wpack, wqkv_b, biasf, y);
  proj_kernel<<<2304, 256, 0, stream>>>(y, wppack, wp_b, out);
}

// Round 22
// 336.106 us; speedup vs baseline: 1.1010x; 1.1010x over previous
//
#include <hip/hip_runtime.h>
#include <hip/hip_bf16.h>

typedef unsigned short u16;
typedef __attribute__((ext_vector_type(8))) short bf16x8;
typedef __attribute__((ext_vector_type(4))) float f32x4;
typedef __attribute__((ext_vector_type(2))) unsigned uint2v;

#define MFMA16(a, b, c) __builtin_amdgcn_mfma_f32_16x16x32_bf16(a, b, c, 0, 0, 0)

__device__ __forceinline__ u16 f2bf(float f) {
  union { float f; unsigned u; } v; v.f = f;
  unsigned r = v.u + 0x7fffu + ((v.u >> 16) & 1u);
  return (u16)(r >> 16);
}

// Pack two f32 -> packed bf16 pair (lo in bits 0..15). Pure C++ (no inline asm).
__device__ __forceinline__ unsigned pkbf(float lo, float hi) {
  union { __hip_bfloat162 h; unsigned u; } v;
  v.h = __hip_bfloat162(__float2bfloat16(lo), __float2bfloat16(hi));
  return v.u;
}

// In-register transpose, permlane edition (r14-verified, bit-identical results):
// input a0/a1 = M[t*16+g*4+r][li] (f32, C-layout of a 32x16 block, t=0,1);
// output frag: lane holds bf16 M[g*8+j][li] — MFMA operand fragment for M^T.
__device__ __forceinline__ bf16x8 xform(f32x4 a0, f32x4 a1) {
  unsigned p0 = pkbf(a0[0], a0[1]), p1 = pkbf(a0[2], a0[3]);
  unsigned p2 = pkbf(a1[0], a1[1]), p3 = pkbf(a1[2], a1[3]);
  uint2v s02 = __builtin_amdgcn_permlane32_swap(p0, p2, false, false);
  uint2v w02 = __builtin_amdgcn_permlane16_swap(s02.x, s02.y, false, false);
  uint2v s13 = __builtin_amdgcn_permlane32_swap(p1, p3, false, false);
  uint2v w13 = __builtin_amdgcn_permlane16_swap(s13.x, s13.y, false, false);
  union { bf16x8 v; unsigned w[4]; } o;
  o.w[0] = w02.x; o.w[1] = w13.x; o.w[2] = w02.y; o.w[3] = w13.y;
  return o.v;
}

// xor-16 / xor-32 lane reductions via permlane-swap (VALU; r14-verified).
__device__ __forceinline__ float pmax16(float v) {
  union { float f; unsigned u; } a; a.f = v;
  uint2v r = __builtin_amdgcn_permlane16_swap(a.u, a.u, false, false);
  union { unsigned u; float f; } x, y; x.u = r.x; y.u = r.y;
  return fmaxf(x.f, y.f);
}
__device__ __forceinline__ float pmax32(float v) {
  union { float f; unsigned u; } a; a.f = v;
  uint2v r = __builtin_amdgcn_permlane32_swap(a.u, a.u, false, false);
  union { unsigned u; float f; } x, y; x.u = r.x; y.u = r.y;
  return fmaxf(x.f, y.f);
}
__device__ __forceinline__ float psum16(float v) {
  union { float f; unsigned u; } a; a.f = v;
  uint2v r = __builtin_amdgcn_permlane16_swap(a.u, a.u, false, false);
  union { unsigned u; float f; } x, y; x.u = r.x; y.u = r.y;
  return x.f + y.f;
}
__device__ __forceinline__ float psum32(float v) {
  union { float f; unsigned u; } a; a.f = v;
  uint2v r = __builtin_amdgcn_permlane32_swap(a.u, a.u, false, false);
  union { unsigned u; float f; } x, y; x.u = r.x; y.u = r.y;
  return x.f + y.f;
}

// ---------------- pack: weights -> bf16 fragment layout, bias -> per-lane frag order ----
__global__ void pack_kernel(const float* __restrict__ wqkv_w,
                            const float* __restrict__ wp_w,
                            const float* __restrict__ bias_table,
                            u16* __restrict__ wpack, u16* __restrict__ wppack,
                            float* __restrict__ biasf) {
  int i = blockIdx.x * 256 + threadIdx.x;
  if (i < 110592) {
    int j = i & 7, l = (i >> 3) & 63;
    int rest = i >> 9;
    int ks = rest % 6, nt = rest / 6;
    int k = ks * 32 + (l >> 4) * 8 + j;
    int n = nt * 16 + (l & 15);
    wpack[i] = f2bf(wqkv_w[k * 576 + n]);
  } else if (i < 147456) {
    int i2 = i - 110592;
    int j = i2 & 7, l = (i2 >> 3) & 63;
    int rest = i2 >> 9;
    int ks = rest % 6, nt = rest / 6;
    int k = ks * 32 + (l >> 4) * 8 + j;
    int n = nt * 16 + (l & 15);
    wppack[i2] = f2bf(wp_w[k * 192 + n]);
  } else if (i < 172032) {
    int i2 = i - 147456;            // 0..24575
    int r = i2 & 3, lane = (i2 >> 2) & 63, mt = (i2 >> 8) & 3, nt = (i2 >> 10) & 3, h = i2 >> 12;
    int q = nt * 16 + (lane & 15);
    int kk = mt * 16 + (lane >> 4) * 4 + r;
    int idx = ((q >> 3) - (kk >> 3) + 7) * 15 + ((q & 7) - (kk & 7) + 7);
    biasf[i2] = bias_table[idx * 6 + h];
  }
}

// ---------------- attn: 1 block = 2 WAVES = 2 HEADS of one window (r20 structure). ----
// r22 change vs r20 (single variable; r21's (128,3) REVERTED — tripwire hit:
// 41 MB scratch, dur +31%): SINGLE-PASS qkv — qt+kt+va accumulated in one sweep
// over ks. r8 proved this exact 1-head single-pass body compiles CLEAN at the
// 256-reg budget (VGPR 96, WRITE exactly ideal; accumulators in AGPRs). Gains:
// af LDS re-reads 72->24 ds_read_b128/wave, 3x independent MFMA chains (better
// overlap at only 2 resident waves/SIMD), 6 weight loads in flight per ks.
// Occupancy is HARD-CAPPED at 2 waves/SIMD (r21 proved 3 spills) — (128,2).
__global__ __launch_bounds__(128, 2) void attn6(
    const float* __restrict__ x, const u16* __restrict__ wpack,
    const float* __restrict__ wqkv_b, const float* __restrict__ biasf,
    u16* __restrict__ y) {
  __shared__ u16 xs[12288];                   // [4 mt][6 ks][64 lane][8] bf16
  const int lane = threadIdx.x & 63;
  const int wv = threadIdx.x >> 6;            // 0,1
  // chunked bijective XCD swizzle: 13824 blocks = 8 XCDs x 1728.
  const int fid = (blockIdx.x & 7) * 1728 + (blockIdx.x >> 3);
  const int w = fid / 3, sub = fid - w * 3;   // window, head-pair
  const int h = sub * 2 + wv;                 // this wave's head
  const int bb = w / 576, rem = w - bb * 576;
  const int wy = rem / 24, wx = rem - (rem / 24) * 24;
  const size_t xbase = (size_t)bb * 36864;
  const int g = lane >> 4, li = lane & 15;

  // per-lane pixel for token (mt*16 + li): pix(mt) = pix0 + mt*384
  const int pix0 = (wy * 8 + (li >> 3)) * 192 + wx * 8 + (li & 7);
  const float* xr = x + (xbase + pix0) * 192 + g * 8;
  const u16* wbase = wpack + lane * 8;

  const float scale = 0.17677669529663687f;   // 1/sqrt(32)
  const f32x4 zero4 = {0.f, 0.f, 0.f, 0.f};

  // ---- stage x -> LDS fragments ONCE (2 waves split 24 chunks: 12 each) ----
#pragma unroll
  for (int ci = 0; ci < 12; ++ci) {
    const int c = wv * 12 + ci, mt = c / 6, ks = c - (c / 6) * 6;
    const float* p = xr + mt * 73728 + ks * 32;   // +mt*384 pixels
    float4 f0 = *(const float4*)p;
    float4 f1 = *(const float4*)(p + 4);
    union { bf16x8 v; unsigned u[4]; } o;
    o.u[0] = pkbf(f0.x, f0.y); o.u[1] = pkbf(f0.z, f0.w);
    o.u[2] = pkbf(f1.x, f1.y); o.u[3] = pkbf(f1.z, f1.w);
    *(bf16x8*)(xs + ((mt * 6 + ks) * 64 + lane) * 8) = o.v;
  }
  __syncthreads();

  // ---- single pass: Q^T, K^T = mfma(W, x_lds); V = mfma(x_lds, W) ----
  f32x4 qt[2][4], kt[2][4], va[4][2];
#pragma unroll
  for (int i = 0; i < 2; ++i)
#pragma unroll
    for (int mt = 0; mt < 4; ++mt) { qt[i][mt] = zero4; kt[i][mt] = zero4; va[mt][i] = zero4; }
#pragma unroll
  for (int ks = 0; ks < 6; ++ks) {
    bf16x8 af[4];
#pragma unroll
    for (int mt = 0; mt < 4; ++mt)
      af[mt] = *(const bf16x8*)(xs + ((mt * 6 + ks) * 64 + lane) * 8);
#pragma unroll
    for (int i = 0; i < 2; ++i) {
      bf16x8 wq = *(const bf16x8*)(wbase + ((2 * h + i) * 6 + ks) * 512);
      bf16x8 wk = *(const bf16x8*)(wbase + ((12 + 2 * h + i) * 6 + ks) * 512);
      bf16x8 wvf = *(const bf16x8*)(wbase + ((24 + 2 * h + i) * 6 + ks) * 512);
#pragma unroll
      for (int mt = 0; mt < 4; ++mt) {
        qt[i][mt] = MFMA16(wq, af[mt], qt[i][mt]);
        kt[i][mt] = MFMA16(wk, af[mt], kt[i][mt]);
        va[mt][i] = MFMA16(af[mt], wvf, va[mt][i]);
      }
    }
  }

  // Q (scaled,+bias), K (+bias) -> S-operand fragments
  f32x4 bq0 = *(const f32x4*)(wqkv_b + h * 32 + g * 4);
  f32x4 bq1 = *(const f32x4*)(wqkv_b + h * 32 + 16 + g * 4);
  f32x4 bk0 = *(const f32x4*)(wqkv_b + 192 + h * 32 + g * 4);
  f32x4 bk1 = *(const f32x4*)(wqkv_b + 192 + h * 32 + 16 + g * 4);
  bf16x8 qf[4], kf[4];
#pragma unroll
  for (int mt = 0; mt < 4; ++mt) {
    qf[mt] = xform((qt[0][mt] + bq0) * scale, (qt[1][mt] + bq1) * scale);
    kf[mt] = xform(kt[0][mt] + bk0, kt[1][mt] + bk1);
  }

  // V (+bias) -> V^T A-operand fragments
  float bva0 = wqkv_b[384 + h * 32 + li], bva1 = wqkv_b[384 + h * 32 + 16 + li];
  bf16x8 vf[2][2];    // [d-tile i][key-chunk ks2]
#pragma unroll
  for (int i = 0; i < 2; ++i) {
    float bv = i ? bva1 : bva0;
#pragma unroll
    for (int ks2 = 0; ks2 < 2; ++ks2)
      vf[i][ks2] = xform(va[ks2 * 2][i] + bv, va[ks2 * 2 + 1][i] + bv);
  }

  // ---- per-q-tile: S^T = mfma(K,Q,bias), softmax, P-frag, PV, fused store ----
  const float* bfh = biasf + h * 4096 + lane * 4;
  u16* yp = y + (size_t)h * 9437184 + (xbase + pix0) * 32 + g * 8;
#pragma unroll
  for (int nt = 0; nt < 4; ++nt) {
    f32x4 em[4];
#pragma unroll
    for (int mt = 0; mt < 4; ++mt) {
      f32x4 bias_c = *(const f32x4*)(bfh + (nt * 4 + mt) * 256);
      em[mt] = MFMA16(kf[mt], qf[nt], bias_c);   // bias folded into C-operand
    }
    float mx = -1e30f;
#pragma unroll
    for (int mt = 0; mt < 4; ++mt)
      mx = fmaxf(mx, fmaxf(fmaxf(em[mt][0], em[mt][1]), fmaxf(em[mt][2], em[mt][3])));
    mx = pmax16(mx);
    mx = pmax32(mx);
    float s = 0.f;
#pragma unroll
    for (int mt = 0; mt < 4; ++mt)
#pragma unroll
      for (int r = 0; r < 4; ++r) { em[mt][r] = __expf(em[mt][r] - mx); s += em[mt][r]; }
    s = psum16(s);
    s = psum32(s);
    float inv = 1.0f / s;
    f32x4 y0 = zero4, y1 = zero4;   // this q-tile's output only
#pragma unroll
    for (int ks2 = 0; ks2 < 2; ++ks2) {
      bf16x8 pf = xform(em[ks2 * 2] * inv, em[ks2 * 2 + 1] * inv);
      y0 = MFMA16(vf[0][ks2], pf, y0);
      y1 = MFMA16(vf[1][ks2], pf, y1);
    }
    // Y^T -> y-fragment; store HEAD-MAJOR y'[h][b*36864 + pix][32]
    bf16x8 yfr = xform(y0, y1);
    *(bf16x8*)(yp + nt * 12288) = yfr;   // +nt*384 pixels * 32 ch
  }
}

// ---------------- projection GEMM: out = y' @ wp + b (head-major y reads) ----------
__global__ __launch_bounds__(256, 2) void proj_kernel(
    const u16* __restrict__ y, const u16* __restrict__ wppack,
    const float* __restrict__ wp_b, float* __restrict__ out) {
  const int tid = threadIdx.x;
  const int lane = tid & 63, wv = tid >> 6;
  const int g = lane >> 4, li = lane & 15;
  const size_t row0 = (size_t)blockIdx.x * 128 + wv * 32;
  const f32x4 zero4 = {0.f, 0.f, 0.f, 0.f};
  f32x4 acc[2][12];
#pragma unroll
  for (int mt = 0; mt < 2; ++mt)
#pragma unroll
    for (int nt = 0; nt < 12; ++nt) acc[mt][nt] = zero4;
#pragma unroll
  for (int ks = 0; ks < 6; ++ks) {
    bf16x8 af[2];
#pragma unroll
    for (int mt = 0; mt < 2; ++mt)
      af[mt] = *(const bf16x8*)(y + (size_t)ks * 9437184 + (row0 + mt * 16 + li) * 32 + g * 8);
#pragma unroll
    for (int nt = 0; nt < 12; ++nt) {
      bf16x8 bf = *(const bf16x8*)(wppack + (nt * 6 + ks) * 512 + lane * 8);
      acc[0][nt] = MFMA16(af[0], bf, acc[0][nt]);
      acc[1][nt] = MFMA16(af[1], bf, acc[1][nt]);
    }
  }
#pragma unroll
  for (int nt = 0; nt < 12; ++nt) {
    float bb = wp_b[nt * 16 + li];
#pragma unroll
    for (int mt = 0; mt < 2; ++mt)
#pragma unroll
      for (int r = 0; r < 4; ++r)
        out[(row0 + mt * 16 + g * 4 + r) * 192 + nt * 16 + li] = acc[mt][nt][r] + bb;
  }
}

extern "C" void kernel_launch(void* const* d_in, const int* in_sizes, int n_in,
                              void* d_out, int out_size, void* d_ws, size_t ws_size,
                              hipStream_t stream) {
  (void)in_sizes; (void)n_in; (void)out_size; (void)ws_size;
  const float* x          = (const float*)d_in[0];
  const float* wqkv_w     = (const float*)d_in[1];
  const float* wqkv_b     = (const float*)d_in[2];
  const float* wp_w       = (const float*)d_in[3];
  const float* wp_b       = (const float*)d_in[4];
  const float* bias_table = (const float*)d_in[5];
  float* out = (float*)d_out;
  char* ws = (char*)d_ws;
  u16* wpack   = (u16*)(ws);              // 221184 B
  u16* wppack  = (u16*)(ws + 221184);     //  73728 B
  float* biasf = (float*)(ws + 294912);   //  98304 B
  u16* y       = (u16*)(ws + 393216);     // 113246208 B (head-major: [6][294912][32])

  pack_kernel<<<672, 256, 0, stream>>>(wqkv_w, wp_w, bias_table, wpack, wppack, biasf);
  attn6<<<13824, 128, 0, stream>>>(x, wpack, wqkv_b, biasf, y);
  proj_kernel<<<2304, 256, 0, stream>>>(y, wppack, wp_b, out);
}

// Round 23
// 302.586 us; speedup vs baseline: 1.2229x; 1.1108x over previous
//
#include <hip/hip_runtime.h>
#include <hip/hip_bf16.h>

typedef unsigned short u16;
typedef __attribute__((ext_vector_type(8))) short bf16x8;
typedef __attribute__((ext_vector_type(4))) float f32x4;
typedef __attribute__((ext_vector_type(2))) unsigned uint2v;

#define MFMA16(a, b, c) __builtin_amdgcn_mfma_f32_16x16x32_bf16(a, b, c, 0, 0, 0)

__device__ __forceinline__ u16 f2bf(float f) {
  union { float f; unsigned u; } v; v.f = f;
  unsigned r = v.u + 0x7fffu + ((v.u >> 16) & 1u);
  return (u16)(r >> 16);
}

// Pack two f32 -> packed bf16 pair (lo in bits 0..15). Pure C++ (no inline asm).
__device__ __forceinline__ unsigned pkbf(float lo, float hi) {
  union { __hip_bfloat162 h; unsigned u; } v;
  v.h = __hip_bfloat162(__float2bfloat16(lo), __float2bfloat16(hi));
  return v.u;
}

// In-register transpose, permlane edition (r14-verified, bit-identical results):
// input a0/a1 = M[t*16+g*4+r][li] (f32, C-layout of a 32x16 block, t=0,1);
// output frag: lane holds bf16 M[g*8+j][li] — MFMA operand fragment for M^T.
__device__ __forceinline__ bf16x8 xform(f32x4 a0, f32x4 a1) {
  unsigned p0 = pkbf(a0[0], a0[1]), p1 = pkbf(a0[2], a0[3]);
  unsigned p2 = pkbf(a1[0], a1[1]), p3 = pkbf(a1[2], a1[3]);
  uint2v s02 = __builtin_amdgcn_permlane32_swap(p0, p2, false, false);
  uint2v w02 = __builtin_amdgcn_permlane16_swap(s02.x, s02.y, false, false);
  uint2v s13 = __builtin_amdgcn_permlane32_swap(p1, p3, false, false);
  uint2v w13 = __builtin_amdgcn_permlane16_swap(s13.x, s13.y, false, false);
  union { bf16x8 v; unsigned w[4]; } o;
  o.w[0] = w02.x; o.w[1] = w13.x; o.w[2] = w02.y; o.w[3] = w13.y;
  return o.v;
}

// xor-16 / xor-32 lane reductions via permlane-swap (VALU; r14-verified).
__device__ __forceinline__ float pmax16(float v) {
  union { float f; unsigned u; } a; a.f = v;
  uint2v r = __builtin_amdgcn_permlane16_swap(a.u, a.u, false, false);
  union { unsigned u; float f; } x, y; x.u = r.x; y.u = r.y;
  return fmaxf(x.f, y.f);
}
__device__ __forceinline__ float pmax32(float v) {
  union { float f; unsigned u; } a; a.f = v;
  uint2v r = __builtin_amdgcn_permlane32_swap(a.u, a.u, false, false);
  union { unsigned u; float f; } x, y; x.u = r.x; y.u = r.y;
  return fmaxf(x.f, y.f);
}
__device__ __forceinline__ float psum16(float v) {
  union { float f; unsigned u; } a; a.f = v;
  uint2v r = __builtin_amdgcn_permlane16_swap(a.u, a.u, false, false);
  union { unsigned u; float f; } x, y; x.u = r.x; y.u = r.y;
  return x.f + y.f;
}
__device__ __forceinline__ float psum32(float v) {
  union { float f; unsigned u; } a; a.f = v;
  uint2v r = __builtin_amdgcn_permlane32_swap(a.u, a.u, false, false);
  union { unsigned u; float f; } x, y; x.u = r.x; y.u = r.y;
  return x.f + y.f;
}

// ---------------- pack: weights -> bf16 fragment layout, bias -> per-lane frag order ----
__global__ void pack_kernel(const float* __restrict__ wqkv_w,
                            const float* __restrict__ wp_w,
                            const float* __restrict__ bias_table,
                            u16* __restrict__ wpack, u16* __restrict__ wppack,
                            float* __restrict__ biasf) {
  int i = blockIdx.x * 256 + threadIdx.x;
  if (i < 110592) {
    int j = i & 7, l = (i >> 3) & 63;
    int rest = i >> 9;
    int ks = rest % 6, nt = rest / 6;
    int k = ks * 32 + (l >> 4) * 8 + j;
    int n = nt * 16 + (l & 15);
    wpack[i] = f2bf(wqkv_w[k * 576 + n]);
  } else if (i < 147456) {
    int i2 = i - 110592;
    int j = i2 & 7, l = (i2 >> 3) & 63;
    int rest = i2 >> 9;
    int ks = rest % 6, nt = rest / 6;
    int k = ks * 32 + (l >> 4) * 8 + j;
    int n = nt * 16 + (l & 15);
    wppack[i2] = f2bf(wp_w[k * 192 + n]);
  } else if (i < 172032) {
    int i2 = i - 147456;            // 0..24575
    int r = i2 & 3, lane = (i2 >> 2) & 63, mt = (i2 >> 8) & 3, nt = (i2 >> 10) & 3, h = i2 >> 12;
    int q = nt * 16 + (lane & 15);
    int kk = mt * 16 + (lane >> 4) * 4 + r;
    int idx = ((q >> 3) - (kk >> 3) + 7) * 15 + ((q & 7) - (kk & 7) + 7);
    biasf[i2] = bias_table[idx * 6 + h];
  }
}

// ---------------- attn: 1 block = 2 WAVES = 2 HEADS of one window (r20 EXACT body). ---
// r23 change vs r20 (single variable; r22's single-pass REVERTED — AGPR-shuffle
// overhead beat its occupancy gain): T5 s_setprio(1) around each MFMA cluster.
// Our waves are barrier-free after staging and sit at different phases (one in a
// qkv MFMA burst while its SIMD-mate runs softmax VALU) — the role-diversity
// regime where T5 measured +4-7% on attn (m191). Register structure untouched:
// r20's 3-pass (128,2) is the proven optimum (r21: 3 waves spills; r22: fewer
// passes -> accvgpr churn).
__global__ __launch_bounds__(128, 2) void attn6(
    const float* __restrict__ x, const u16* __restrict__ wpack,
    const float* __restrict__ wqkv_b, const float* __restrict__ biasf,
    u16* __restrict__ y) {
  __shared__ u16 xs[12288];                   // [4 mt][6 ks][64 lane][8] bf16
  const int lane = threadIdx.x & 63;
  const int wv = threadIdx.x >> 6;            // 0,1
  // chunked bijective XCD swizzle: 13824 blocks = 8 XCDs x 1728.
  const int fid = (blockIdx.x & 7) * 1728 + (blockIdx.x >> 3);
  const int w = fid / 3, sub = fid - w * 3;   // window, head-pair
  const int h = sub * 2 + wv;                 // this wave's head
  const int bb = w / 576, rem = w - bb * 576;
  const int wy = rem / 24, wx = rem - (rem / 24) * 24;
  const size_t xbase = (size_t)bb * 36864;
  const int g = lane >> 4, li = lane & 15;

  // per-lane pixel for token (mt*16 + li): pix(mt) = pix0 + mt*384
  const int pix0 = (wy * 8 + (li >> 3)) * 192 + wx * 8 + (li & 7);
  const float* xr = x + (xbase + pix0) * 192 + g * 8;
  const u16* wbase = wpack + lane * 8;

  const float scale = 0.17677669529663687f;   // 1/sqrt(32)
  const f32x4 zero4 = {0.f, 0.f, 0.f, 0.f};

  // ---- stage x -> LDS fragments ONCE (2 waves split 24 chunks: 12 each) ----
#pragma unroll
  for (int ci = 0; ci < 12; ++ci) {
    const int c = wv * 12 + ci, mt = c / 6, ks = c - (c / 6) * 6;
    const float* p = xr + mt * 73728 + ks * 32;   // +mt*384 pixels
    float4 f0 = *(const float4*)p;
    float4 f1 = *(const float4*)(p + 4);
    union { bf16x8 v; unsigned u[4]; } o;
    o.u[0] = pkbf(f0.x, f0.y); o.u[1] = pkbf(f0.z, f0.w);
    o.u[2] = pkbf(f1.x, f1.y); o.u[3] = pkbf(f1.z, f1.w);
    *(bf16x8*)(xs + ((mt * 6 + ks) * 64 + lane) * 8) = o.v;
  }
  __syncthreads();

  // ---- pass Q: Q^T = mfma(Wq, x_lds)  (32-reg accumulator block) ----
  bf16x8 qf[4];
  {
    f32x4 qt[2][4];
#pragma unroll
    for (int i = 0; i < 2; ++i)
#pragma unroll
      for (int mt = 0; mt < 4; ++mt) qt[i][mt] = zero4;
    __builtin_amdgcn_s_setprio(1);
#pragma unroll
    for (int ks = 0; ks < 6; ++ks) {
      bf16x8 af[4];
#pragma unroll
      for (int mt = 0; mt < 4; ++mt)
        af[mt] = *(const bf16x8*)(xs + ((mt * 6 + ks) * 64 + lane) * 8);
#pragma unroll
      for (int i = 0; i < 2; ++i) {
        bf16x8 wq = *(const bf16x8*)(wbase + ((2 * h + i) * 6 + ks) * 512);
#pragma unroll
        for (int mt = 0; mt < 4; ++mt) qt[i][mt] = MFMA16(wq, af[mt], qt[i][mt]);
      }
    }
    __builtin_amdgcn_s_setprio(0);
    f32x4 bq0 = *(const f32x4*)(wqkv_b + h * 32 + g * 4);
    f32x4 bq1 = *(const f32x4*)(wqkv_b + h * 32 + 16 + g * 4);
#pragma unroll
    for (int mt = 0; mt < 4; ++mt)
      qf[mt] = xform((qt[0][mt] + bq0) * scale, (qt[1][mt] + bq1) * scale);
  }

  // ---- pass K: K^T = mfma(Wk, x_lds)  (32-reg accumulator block) ----
  bf16x8 kf[4];
  {
    f32x4 kt[2][4];
#pragma unroll
    for (int i = 0; i < 2; ++i)
#pragma unroll
      for (int mt = 0; mt < 4; ++mt) kt[i][mt] = zero4;
    __builtin_amdgcn_s_setprio(1);
#pragma unroll
    for (int ks = 0; ks < 6; ++ks) {
      bf16x8 af[4];
#pragma unroll
      for (int mt = 0; mt < 4; ++mt)
        af[mt] = *(const bf16x8*)(xs + ((mt * 6 + ks) * 64 + lane) * 8);
#pragma unroll
      for (int i = 0; i < 2; ++i) {
        bf16x8 wk = *(const bf16x8*)(wbase + ((12 + 2 * h + i) * 6 + ks) * 512);
#pragma unroll
        for (int mt = 0; mt < 4; ++mt) kt[i][mt] = MFMA16(wk, af[mt], kt[i][mt]);
      }
    }
    __builtin_amdgcn_s_setprio(0);
    f32x4 bk0 = *(const f32x4*)(wqkv_b + 192 + h * 32 + g * 4);
    f32x4 bk1 = *(const f32x4*)(wqkv_b + 192 + h * 32 + 16 + g * 4);
#pragma unroll
    for (int mt = 0; mt < 4; ++mt)
      kf[mt] = xform(kt[0][mt] + bk0, kt[1][mt] + bk1);
  }

  // ---- pass V: V = mfma(x_lds, Wv)  (32-reg accumulator block) ----
  bf16x8 vf[2][2];    // [d-tile i][key-chunk ks2] — V^T A-operand
  {
    f32x4 va[4][2];
#pragma unroll
    for (int mt = 0; mt < 4; ++mt) { va[mt][0] = zero4; va[mt][1] = zero4; }
    __builtin_amdgcn_s_setprio(1);
#pragma unroll
    for (int ks = 0; ks < 6; ++ks) {
      bf16x8 af[4];
#pragma unroll
      for (int mt = 0; mt < 4; ++mt)
        af[mt] = *(const bf16x8*)(xs + ((mt * 6 + ks) * 64 + lane) * 8);
      bf16x8 wv0 = *(const bf16x8*)(wbase + ((24 + 2 * h) * 6 + ks) * 512);
      bf16x8 wv1 = *(const bf16x8*)(wbase + ((25 + 2 * h) * 6 + ks) * 512);
#pragma unroll
      for (int mt = 0; mt < 4; ++mt) {
        va[mt][0] = MFMA16(af[mt], wv0, va[mt][0]);
        va[mt][1] = MFMA16(af[mt], wv1, va[mt][1]);
      }
    }
    __builtin_amdgcn_s_setprio(0);
    float bva0 = wqkv_b[384 + h * 32 + li], bva1 = wqkv_b[384 + h * 32 + 16 + li];
#pragma unroll
    for (int i = 0; i < 2; ++i) {
      float bv = i ? bva1 : bva0;
#pragma unroll
      for (int ks2 = 0; ks2 < 2; ++ks2)
        vf[i][ks2] = xform(va[ks2 * 2][i] + bv, va[ks2 * 2 + 1][i] + bv);
    }
  }

  // ---- per-q-tile: S^T = mfma(K,Q,bias), softmax, P-frag, PV, fused store ----
  const float* bfh = biasf + h * 4096 + lane * 4;
  u16* yp = y + (size_t)h * 9437184 + (xbase + pix0) * 32 + g * 8;
#pragma unroll
  for (int nt = 0; nt < 4; ++nt) {
    f32x4 em[4];
    __builtin_amdgcn_s_setprio(1);
#pragma unroll
    for (int mt = 0; mt < 4; ++mt) {
      f32x4 bias_c = *(const f32x4*)(bfh + (nt * 4 + mt) * 256);
      em[mt] = MFMA16(kf[mt], qf[nt], bias_c);   // bias folded into C-operand
    }
    __builtin_amdgcn_s_setprio(0);
    float mx = -1e30f;
#pragma unroll
    for (int mt = 0; mt < 4; ++mt)
      mx = fmaxf(mx, fmaxf(fmaxf(em[mt][0], em[mt][1]), fmaxf(em[mt][2], em[mt][3])));
    mx = pmax16(mx);
    mx = pmax32(mx);
    float s = 0.f;
#pragma unroll
    for (int mt = 0; mt < 4; ++mt)
#pragma unroll
      for (int r = 0; r < 4; ++r) { em[mt][r] = __expf(em[mt][r] - mx); s += em[mt][r]; }
    s = psum16(s);
    s = psum32(s);
    float inv = 1.0f / s;
    f32x4 y0 = zero4, y1 = zero4;   // this q-tile's output only
    __builtin_amdgcn_s_setprio(1);
#pragma unroll
    for (int ks2 = 0; ks2 < 2; ++ks2) {
      bf16x8 pf = xform(em[ks2 * 2] * inv, em[ks2 * 2 + 1] * inv);
      y0 = MFMA16(vf[0][ks2], pf, y0);
      y1 = MFMA16(vf[1][ks2], pf, y1);
    }
    __builtin_amdgcn_s_setprio(0);
    // Y^T -> y-fragment; store HEAD-MAJOR y'[h][b*36864 + pix][32]
    bf16x8 yfr = xform(y0, y1);
    *(bf16x8*)(yp + nt * 12288) = yfr;   // +nt*384 pixels * 32 ch
  }
}

// ---------------- projection GEMM: out = y' @ wp + b (head-major y reads) ----------
__global__ __launch_bounds__(256, 2) void proj_kernel(
    const u16* __restrict__ y, const u16* __restrict__ wppack,
    const float* __restrict__ wp_b, float* __restrict__ out) {
  const int tid = threadIdx.x;
  const int lane = tid & 63, wv = tid >> 6;
  const int g = lane >> 4, li = lane & 15;
  const size_t row0 = (size_t)blockIdx.x * 128 + wv * 32;
  const f32x4 zero4 = {0.f, 0.f, 0.f, 0.f};
  f32x4 acc[2][12];
#pragma unroll
  for (int mt = 0; mt < 2; ++mt)
#pragma unroll
    for (int nt = 0; nt < 12; ++nt) acc[mt][nt] = zero4;
#pragma unroll
  for (int ks = 0; ks < 6; ++ks) {
    bf16x8 af[2];
#pragma unroll
    for (int mt = 0; mt < 2; ++mt)
      af[mt] = *(const bf16x8*)(y + (size_t)ks * 9437184 + (row0 + mt * 16 + li) * 32 + g * 8);
#pragma unroll
    for (int nt = 0; nt < 12; ++nt) {
      bf16x8 bf = *(const bf16x8*)(wppack + (nt * 6 + ks) * 512 + lane * 8);
      acc[0][nt] = MFMA16(af[0], bf, acc[0][nt]);
      acc[1][nt] = MFMA16(af[1], bf, acc[1][nt]);
    }
  }
#pragma unroll
  for (int nt = 0; nt < 12; ++nt) {
    float bb = wp_b[nt * 16 + li];
#pragma unroll
    for (int mt = 0; mt < 2; ++mt)
#pragma unroll
      for (int r = 0; r < 4; ++r)
        out[(row0 + mt * 16 + g * 4 + r) * 192 + nt * 16 + li] = acc[mt][nt][r] + bb;
  }
}

extern "C" void kernel_launch(void* const* d_in, const int* in_sizes, int n_in,
                              void* d_out, int out_size, void* d_ws, size_t ws_size,
                              hipStream_t stream) {
  (void)in_sizes; (void)n_in; (void)out_size; (void)ws_size;
  const float* x          = (const float*)d_in[0];
  const float* wqkv_w     = (const float*)d_in[1];
  const float* wqkv_b     = (const float*)d_in[2];
  const float* wp_w       = (const float*)d_in[3];
  const float* wp_b       = (const float*)d_in[4];
  const float* bias_table = (const float*)d_in[5];
  float* out = (float*)d_out;
  char* ws = (char*)d_ws;
  u16* wpack   = (u16*)(ws);              // 221184 B
  u16* wppack  = (u16*)(ws + 221184);     //  73728 B
  float* biasf = (float*)(ws + 294912);   //  98304 B
  u16* y       = (u16*)(ws + 393216);     // 113246208 B (head-major: [6][294912][32])

  pack_kernel<<<672, 256, 0, stream>>>(wqkv_w, wp_w, bias_table, wpack, wppack, biasf);
  attn6<<<13824, 128, 0, stream>>>(x, wpack, wqkv_b, biasf, y);
  proj_kernel<<<2304, 256, 0, stream>>>(y, wppack, wp_b, out);
}

// Round 24
// 300.156 us; speedup vs baseline: 1.2328x; 1.0081x over previous
//
#include <hip/hip_runtime.h>
#include <hip/hip_bf16.h>

typedef unsigned short u16;
typedef __attribute__((ext_vector_type(8))) short bf16x8;
typedef __attribute__((ext_vector_type(4))) float f32x4;
typedef __attribute__((ext_vector_type(2))) unsigned uint2v;

#define MFMA16(a, b, c) __builtin_amdgcn_mfma_f32_16x16x32_bf16(a, b, c, 0, 0, 0)

__device__ __forceinline__ u16 f2bf(float f) {
  union { float f; unsigned u; } v; v.f = f;
  unsigned r = v.u + 0x7fffu + ((v.u >> 16) & 1u);
  return (u16)(r >> 16);
}

// Pack two f32 -> packed bf16 pair (lo in bits 0..15). Pure C++ (no inline asm).
__device__ __forceinline__ unsigned pkbf(float lo, float hi) {
  union { __hip_bfloat162 h; unsigned u; } v;
  v.h = __hip_bfloat162(__float2bfloat16(lo), __float2bfloat16(hi));
  return v.u;
}

// In-register transpose, permlane edition (r14-verified, bit-identical results):
// input a0/a1 = M[t*16+g*4+r][li] (f32, C-layout of a 32x16 block, t=0,1);
// output frag: lane holds bf16 M[g*8+j][li] — MFMA operand fragment for M^T.
__device__ __forceinline__ bf16x8 xform(f32x4 a0, f32x4 a1) {
  unsigned p0 = pkbf(a0[0], a0[1]), p1 = pkbf(a0[2], a0[3]);
  unsigned p2 = pkbf(a1[0], a1[1]), p3 = pkbf(a1[2], a1[3]);
  uint2v s02 = __builtin_amdgcn_permlane32_swap(p0, p2, false, false);
  uint2v w02 = __builtin_amdgcn_permlane16_swap(s02.x, s02.y, false, false);
  uint2v s13 = __builtin_amdgcn_permlane32_swap(p1, p3, false, false);
  uint2v w13 = __builtin_amdgcn_permlane16_swap(s13.x, s13.y, false, false);
  union { bf16x8 v; unsigned w[4]; } o;
  o.w[0] = w02.x; o.w[1] = w13.x; o.w[2] = w02.y; o.w[3] = w13.y;
  return o.v;
}

// xor-16 / xor-32 lane reductions via permlane-swap (VALU; r14-verified).
__device__ __forceinline__ float pmax16(float v) {
  union { float f; unsigned u; } a; a.f = v;
  uint2v r = __builtin_amdgcn_permlane16_swap(a.u, a.u, false, false);
  union { unsigned u; float f; } x, y; x.u = r.x; y.u = r.y;
  return fmaxf(x.f, y.f);
}
__device__ __forceinline__ float pmax32(float v) {
  union { float f; unsigned u; } a; a.f = v;
  uint2v r = __builtin_amdgcn_permlane32_swap(a.u, a.u, false, false);
  union { unsigned u; float f; } x, y; x.u = r.x; y.u = r.y;
  return fmaxf(x.f, y.f);
}
__device__ __forceinline__ float psum16(float v) {
  union { float f; unsigned u; } a; a.f = v;
  uint2v r = __builtin_amdgcn_permlane16_swap(a.u, a.u, false, false);
  union { unsigned u; float f; } x, y; x.u = r.x; y.u = r.y;
  return x.f + y.f;
}
__device__ __forceinline__ float psum32(float v) {
  union { float f; unsigned u; } a; a.f = v;
  uint2v r = __builtin_amdgcn_permlane32_swap(a.u, a.u, false, false);
  union { unsigned u; float f; } x, y; x.u = r.x; y.u = r.y;
  return x.f + y.f;
}

// ---------------- pack: weights -> bf16 fragment layout, bias -> per-lane frag order ----
__global__ void pack_kernel(const float* __restrict__ wqkv_w,
                            const float* __restrict__ wp_w,
                            const float* __restrict__ bias_table,
                            u16* __restrict__ wpack, u16* __restrict__ wppack,
                            float* __restrict__ biasf) {
  int i = blockIdx.x * 256 + threadIdx.x;
  if (i < 110592) {
    int j = i & 7, l = (i >> 3) & 63;
    int rest = i >> 9;
    int ks = rest % 6, nt = rest / 6;
    int k = ks * 32 + (l >> 4) * 8 + j;
    int n = nt * 16 + (l & 15);
    wpack[i] = f2bf(wqkv_w[k * 576 + n]);
  } else if (i < 147456) {
    int i2 = i - 110592;
    int j = i2 & 7, l = (i2 >> 3) & 63;
    int rest = i2 >> 9;
    int ks = rest % 6, nt = rest / 6;
    int k = ks * 32 + (l >> 4) * 8 + j;
    int n = nt * 16 + (l & 15);
    wppack[i2] = f2bf(wp_w[k * 192 + n]);
  } else if (i < 172032) {
    int i2 = i - 147456;            // 0..24575
    int r = i2 & 3, lane = (i2 >> 2) & 63, mt = (i2 >> 8) & 3, nt = (i2 >> 10) & 3, h = i2 >> 12;
    int q = nt * 16 + (lane & 15);
    int kk = mt * 16 + (lane >> 4) * 4 + r;
    int idx = ((q >> 3) - (kk >> 3) + 7) * 15 + ((q & 7) - (kk & 7) + 7);
    biasf[i2] = bias_table[idx * 6 + h];
  }
}

// ---------------- attn: 1 block = 2 WAVES = 2 HEADS of one window (r23 + 2-pass). -----
// r24 change vs r23 (single variable): Q and K passes MERGED (qt+kt = 64 acc live
// together). r23 compiled to VGPR 68 — ~60 regs of arch headroom under the
// (128,2) clean cap — so the +32 acc fits. Gains: 16 independent MFMA chains in
// the merged pass (halved dependency stalls), one fewer xs sweep (48->36
// ds_read_b128), K weight loads issue under Q compute. TRIPWIRE: WRITE >= 125 MB
// (spill) or dur >= 212 us -> r23 is this structure's floor.
__global__ __launch_bounds__(128, 2) void attn6(
    const float* __restrict__ x, const u16* __restrict__ wpack,
    const float* __restrict__ wqkv_b, const float* __restrict__ biasf,
    u16* __restrict__ y) {
  __shared__ u16 xs[12288];                   // [4 mt][6 ks][64 lane][8] bf16
  const int lane = threadIdx.x & 63;
  const int wv = threadIdx.x >> 6;            // 0,1
  // chunked bijective XCD swizzle: 13824 blocks = 8 XCDs x 1728.
  const int fid = (blockIdx.x & 7) * 1728 + (blockIdx.x >> 3);
  const int w = fid / 3, sub = fid - w * 3;   // window, head-pair
  const int h = sub * 2 + wv;                 // this wave's head
  const int bb = w / 576, rem = w - bb * 576;
  const int wy = rem / 24, wx = rem - (rem / 24) * 24;
  const size_t xbase = (size_t)bb * 36864;
  const int g = lane >> 4, li = lane & 15;

  // per-lane pixel for token (mt*16 + li): pix(mt) = pix0 + mt*384
  const int pix0 = (wy * 8 + (li >> 3)) * 192 + wx * 8 + (li & 7);
  const float* xr = x + (xbase + pix0) * 192 + g * 8;
  const u16* wbase = wpack + lane * 8;

  const float scale = 0.17677669529663687f;   // 1/sqrt(32)
  const f32x4 zero4 = {0.f, 0.f, 0.f, 0.f};

  // ---- stage x -> LDS fragments ONCE (2 waves split 24 chunks: 12 each) ----
#pragma unroll
  for (int ci = 0; ci < 12; ++ci) {
    const int c = wv * 12 + ci, mt = c / 6, ks = c - (c / 6) * 6;
    const float* p = xr + mt * 73728 + ks * 32;   // +mt*384 pixels
    float4 f0 = *(const float4*)p;
    float4 f1 = *(const float4*)(p + 4);
    union { bf16x8 v; unsigned u[4]; } o;
    o.u[0] = pkbf(f0.x, f0.y); o.u[1] = pkbf(f0.z, f0.w);
    o.u[2] = pkbf(f1.x, f1.y); o.u[3] = pkbf(f1.z, f1.w);
    *(bf16x8*)(xs + ((mt * 6 + ks) * 64 + lane) * 8) = o.v;
  }
  __syncthreads();

  // ---- pass QK: Q^T, K^T = mfma(W, x_lds)  (64-reg accumulator block) ----
  bf16x8 qf[4], kf[4];
  {
    f32x4 qt[2][4], kt[2][4];
#pragma unroll
    for (int i = 0; i < 2; ++i)
#pragma unroll
      for (int mt = 0; mt < 4; ++mt) { qt[i][mt] = zero4; kt[i][mt] = zero4; }
    __builtin_amdgcn_s_setprio(1);
#pragma unroll
    for (int ks = 0; ks < 6; ++ks) {
      bf16x8 af[4];
#pragma unroll
      for (int mt = 0; mt < 4; ++mt)
        af[mt] = *(const bf16x8*)(xs + ((mt * 6 + ks) * 64 + lane) * 8);
#pragma unroll
      for (int i = 0; i < 2; ++i) {
        bf16x8 wq = *(const bf16x8*)(wbase + ((2 * h + i) * 6 + ks) * 512);
        bf16x8 wk = *(const bf16x8*)(wbase + ((12 + 2 * h + i) * 6 + ks) * 512);
#pragma unroll
        for (int mt = 0; mt < 4; ++mt) {
          qt[i][mt] = MFMA16(wq, af[mt], qt[i][mt]);
          kt[i][mt] = MFMA16(wk, af[mt], kt[i][mt]);
        }
      }
    }
    __builtin_amdgcn_s_setprio(0);
    f32x4 bq0 = *(const f32x4*)(wqkv_b + h * 32 + g * 4);
    f32x4 bq1 = *(const f32x4*)(wqkv_b + h * 32 + 16 + g * 4);
    f32x4 bk0 = *(const f32x4*)(wqkv_b + 192 + h * 32 + g * 4);
    f32x4 bk1 = *(const f32x4*)(wqkv_b + 192 + h * 32 + 16 + g * 4);
#pragma unroll
    for (int mt = 0; mt < 4; ++mt) {
      qf[mt] = xform((qt[0][mt] + bq0) * scale, (qt[1][mt] + bq1) * scale);
      kf[mt] = xform(kt[0][mt] + bk0, kt[1][mt] + bk1);
    }
  }

  // ---- pass V: V = mfma(x_lds, Wv)  (32-reg accumulator block) ----
  bf16x8 vf[2][2];    // [d-tile i][key-chunk ks2] — V^T A-operand
  {
    f32x4 va[4][2];
#pragma unroll
    for (int mt = 0; mt < 4; ++mt) { va[mt][0] = zero4; va[mt][1] = zero4; }
    __builtin_amdgcn_s_setprio(1);
#pragma unroll
    for (int ks = 0; ks < 6; ++ks) {
      bf16x8 af[4];
#pragma unroll
      for (int mt = 0; mt < 4; ++mt)
        af[mt] = *(const bf16x8*)(xs + ((mt * 6 + ks) * 64 + lane) * 8);
      bf16x8 wv0 = *(const bf16x8*)(wbase + ((24 + 2 * h) * 6 + ks) * 512);
      bf16x8 wv1 = *(const bf16x8*)(wbase + ((25 + 2 * h) * 6 + ks) * 512);
#pragma unroll
      for (int mt = 0; mt < 4; ++mt) {
        va[mt][0] = MFMA16(af[mt], wv0, va[mt][0]);
        va[mt][1] = MFMA16(af[mt], wv1, va[mt][1]);
      }
    }
    __builtin_amdgcn_s_setprio(0);
    float bva0 = wqkv_b[384 + h * 32 + li], bva1 = wqkv_b[384 + h * 32 + 16 + li];
#pragma unroll
    for (int i = 0; i < 2; ++i) {
      float bv = i ? bva1 : bva0;
#pragma unroll
      for (int ks2 = 0; ks2 < 2; ++ks2)
        vf[i][ks2] = xform(va[ks2 * 2][i] + bv, va[ks2 * 2 + 1][i] + bv);
    }
  }

  // ---- per-q-tile: S^T = mfma(K,Q,bias), softmax, P-frag, PV, fused store ----
  const float* bfh = biasf + h * 4096 + lane * 4;
  u16* yp = y + (size_t)h * 9437184 + (xbase + pix0) * 32 + g * 8;
#pragma unroll
  for (int nt = 0; nt < 4; ++nt) {
    f32x4 em[4];
    __builtin_amdgcn_s_setprio(1);
#pragma unroll
    for (int mt = 0; mt < 4; ++mt) {
      f32x4 bias_c = *(const f32x4*)(bfh + (nt * 4 + mt) * 256);
      em[mt] = MFMA16(kf[mt], qf[nt], bias_c);   // bias folded into C-operand
    }
    __builtin_amdgcn_s_setprio(0);
    float mx = -1e30f;
#pragma unroll
    for (int mt = 0; mt < 4; ++mt)
      mx = fmaxf(mx, fmaxf(fmaxf(em[mt][0], em[mt][1]), fmaxf(em[mt][2], em[mt][3])));
    mx = pmax16(mx);
    mx = pmax32(mx);
    float s = 0.f;
#pragma unroll
    for (int mt = 0; mt < 4; ++mt)
#pragma unroll
      for (int r = 0; r < 4; ++r) { em[mt][r] = __expf(em[mt][r] - mx); s += em[mt][r]; }
    s = psum16(s);
    s = psum32(s);
    float inv = 1.0f / s;
    f32x4 y0 = zero4, y1 = zero4;   // this q-tile's output only
    __builtin_amdgcn_s_setprio(1);
#pragma unroll
    for (int ks2 = 0; ks2 < 2; ++ks2) {
      bf16x8 pf = xform(em[ks2 * 2] * inv, em[ks2 * 2 + 1] * inv);
      y0 = MFMA16(vf[0][ks2], pf, y0);
      y1 = MFMA16(vf[1][ks2], pf, y1);
    }
    __builtin_amdgcn_s_setprio(0);
    // Y^T -> y-fragment; store HEAD-MAJOR y'[h][b*36864 + pix][32]
    bf16x8 yfr = xform(y0, y1);
    *(bf16x8*)(yp + nt * 12288) = yfr;   // +nt*384 pixels * 32 ch
  }
}

// ---------------- projection GEMM: out = y' @ wp + b (head-major y reads) ----------
__global__ __launch_bounds__(256, 2) void proj_kernel(
    const u16* __restrict__ y, const u16* __restrict__ wppack,
    const float* __restrict__ wp_b, float* __restrict__ out) {
  const int tid = threadIdx.x;
  const int lane = tid & 63, wv = tid >> 6;
  const int g = lane >> 4, li = lane & 15;
  const size_t row0 = (size_t)blockIdx.x * 128 + wv * 32;
  const f32x4 zero4 = {0.f, 0.f, 0.f, 0.f};
  f32x4 acc[2][12];
#pragma unroll
  for (int mt = 0; mt < 2; ++mt)
#pragma unroll
    for (int nt = 0; nt < 12; ++nt) acc[mt][nt] = zero4;
#pragma unroll
  for (int ks = 0; ks < 6; ++ks) {
    bf16x8 af[2];
#pragma unroll
    for (int mt = 0; mt < 2; ++mt)
      af[mt] = *(const bf16x8*)(y + (size_t)ks * 9437184 + (row0 + mt * 16 + li) * 32 + g * 8);
#pragma unroll
    for (int nt = 0; nt < 12; ++nt) {
      bf16x8 bf = *(const bf16x8*)(wppack + (nt * 6 + ks) * 512 + lane * 8);
      acc[0][nt] = MFMA16(af[0], bf, acc[0][nt]);
      acc[1][nt] = MFMA16(af[1], bf, acc[1][nt]);
    }
  }
#pragma unroll
  for (int nt = 0; nt < 12; ++nt) {
    float bb = wp_b[nt * 16 + li];
#pragma unroll
    for (int mt = 0; mt < 2; ++mt)
#pragma unroll
      for (int r = 0; r < 4; ++r)
        out[(row0 + mt * 16 + g * 4 + r) * 192 + nt * 16 + li] = acc[mt][nt][r] + bb;
  }
}

extern "C" void kernel_launch(void* const* d_in, const int* in_sizes, int n_in,
                              void* d_out, int out_size, void* d_ws, size_t ws_size,
                              hipStream_t stream) {
  (void)in_sizes; (void)n_in; (void)out_size; (void)ws_size;
  const float* x          = (const float*)d_in[0];
  const float* wqkv_w     = (const float*)d_in[1];
  const float* wqkv_b     = (const float*)d_in[2];
  const float* wp_w       = (const float*)d_in[3];
  const float* wp_b       = (const float*)d_in[4];
  const float* bias_table = (const float*)d_in[5];
  float* out = (float*)d_out;
  char* ws = (char*)d_ws;
  u16* wpack   = (u16*)(ws);              // 221184 B
  u16* wppack  = (u16*)(ws + 221184);     //  73728 B
  float* biasf = (float*)(ws + 294912);   //  98304 B
  u16* y       = (u16*)(ws + 393216);     // 113246208 B (head-major: [6][294912][32])

  pack_kernel<<<672, 256, 0, stream>>>(wqkv_w, wp_w, bias_table, wpack, wppack, biasf);
  attn6<<<13824, 128, 0, stream>>>(x, wpack, wqkv_b, biasf, y);
  proj_kernel<<<2304, 256, 0, stream>>>(y, wppack, wp_b, out);
}

// Round 25
// 289.366 us; speedup vs baseline: 1.2788x; 1.0373x over previous
//
#include <hip/hip_runtime.h>
#include <hip/hip_bf16.h>

typedef unsigned short u16;
typedef __attribute__((ext_vector_type(8))) short bf16x8;
typedef __attribute__((ext_vector_type(4))) float f32x4;
typedef __attribute__((ext_vector_type(2))) unsigned uint2v;

#define MFMA16(a, b, c) __builtin_amdgcn_mfma_f32_16x16x32_bf16(a, b, c, 0, 0, 0)

__device__ __forceinline__ u16 f2bf(float f) {
  union { float f; unsigned u; } v; v.f = f;
  unsigned r = v.u + 0x7fffu + ((v.u >> 16) & 1u);
  return (u16)(r >> 16);
}

// Pack two f32 -> packed bf16 pair (lo in bits 0..15). Pure C++ (no inline asm).
__device__ __forceinline__ unsigned pkbf(float lo, float hi) {
  union { __hip_bfloat162 h; unsigned u; } v;
  v.h = __hip_bfloat162(__float2bfloat16(lo), __float2bfloat16(hi));
  return v.u;
}

// In-register transpose, permlane edition (r14-verified, bit-identical results):
// input a0/a1 = M[t*16+g*4+r][li] (f32, C-layout of a 32x16 block, t=0,1);
// output frag: lane holds bf16 M[g*8+j][li] — MFMA operand fragment for M^T.
__device__ __forceinline__ bf16x8 xform(f32x4 a0, f32x4 a1) {
  unsigned p0 = pkbf(a0[0], a0[1]), p1 = pkbf(a0[2], a0[3]);
  unsigned p2 = pkbf(a1[0], a1[1]), p3 = pkbf(a1[2], a1[3]);
  uint2v s02 = __builtin_amdgcn_permlane32_swap(p0, p2, false, false);
  uint2v w02 = __builtin_amdgcn_permlane16_swap(s02.x, s02.y, false, false);
  uint2v s13 = __builtin_amdgcn_permlane32_swap(p1, p3, false, false);
  uint2v w13 = __builtin_amdgcn_permlane16_swap(s13.x, s13.y, false, false);
  union { bf16x8 v; unsigned w[4]; } o;
  o.w[0] = w02.x; o.w[1] = w13.x; o.w[2] = w02.y; o.w[3] = w13.y;
  return o.v;
}

// xor-16 / xor-32 lane reductions via permlane-swap (VALU; r14-verified).
__device__ __forceinline__ float pmax16(float v) {
  union { float f; unsigned u; } a; a.f = v;
  uint2v r = __builtin_amdgcn_permlane16_swap(a.u, a.u, false, false);
  union { unsigned u; float f; } x, y; x.u = r.x; y.u = r.y;
  return fmaxf(x.f, y.f);
}
__device__ __forceinline__ float pmax32(float v) {
  union { float f; unsigned u; } a; a.f = v;
  uint2v r = __builtin_amdgcn_permlane32_swap(a.u, a.u, false, false);
  union { unsigned u; float f; } x, y; x.u = r.x; y.u = r.y;
  return fmaxf(x.f, y.f);
}
__device__ __forceinline__ float psum16(float v) {
  union { float f; unsigned u; } a; a.f = v;
  uint2v r = __builtin_amdgcn_permlane16_swap(a.u, a.u, false, false);
  union { unsigned u; float f; } x, y; x.u = r.x; y.u = r.y;
  return x.f + y.f;
}
__device__ __forceinline__ float psum32(float v) {
  union { float f; unsigned u; } a; a.f = v;
  uint2v r = __builtin_amdgcn_permlane32_swap(a.u, a.u, false, false);
  union { unsigned u; float f; } x, y; x.u = r.x; y.u = r.y;
  return x.f + y.f;
}

// ---------------- pack: weights -> bf16 fragment layout, bias -> per-lane frag order ----
__global__ void pack_kernel(const float* __restrict__ wqkv_w,
                            const float* __restrict__ wp_w,
                            const float* __restrict__ bias_table,
                            u16* __restrict__ wpack, u16* __restrict__ wppack,
                            float* __restrict__ biasf) {
  int i = blockIdx.x * 256 + threadIdx.x;
  if (i < 110592) {
    int j = i & 7, l = (i >> 3) & 63;
    int rest = i >> 9;
    int ks = rest % 6, nt = rest / 6;
    int k = ks * 32 + (l >> 4) * 8 + j;
    int n = nt * 16 + (l & 15);
    wpack[i] = f2bf(wqkv_w[k * 576 + n]);
  } else if (i < 147456) {
    int i2 = i - 110592;
    int j = i2 & 7, l = (i2 >> 3) & 63;
    int rest = i2 >> 9;
    int ks = rest % 6, nt = rest / 6;
    int k = ks * 32 + (l >> 4) * 8 + j;
    int n = nt * 16 + (l & 15);
    wppack[i2] = f2bf(wp_w[k * 192 + n]);
  } else if (i < 172032) {
    int i2 = i - 147456;            // 0..24575
    int r = i2 & 3, lane = (i2 >> 2) & 63, mt = (i2 >> 8) & 3, nt = (i2 >> 10) & 3, h = i2 >> 12;
    int q = nt * 16 + (lane & 15);
    int kk = mt * 16 + (lane >> 4) * 4 + r;
    int idx = ((q >> 3) - (kk >> 3) + 7) * 15 + ((q & 7) - (kk & 7) + 7);
    biasf[i2] = bias_table[idx * 6 + h];
  }
}

// ---------------- attn: 1 block = 2 WAVES = 2 HEADS of one window (r24 EXACT). --------
// Best measured config (r24: attn 211 us, VGPR 72, WRITE/FETCH exactly ideal,
// occupancy 32% ~ the 6-block LDS ceiling). Register/occupancy trade-space
// exhaustively mapped: r21 (3 waves) spills; r22 (1-pass) churns AGPRs;
// r23 (3-pass) == r24 within noise. FROZEN.
__global__ __launch_bounds__(128, 2) void attn6(
    const float* __restrict__ x, const u16* __restrict__ wpack,
    const float* __restrict__ wqkv_b, const float* __restrict__ biasf,
    u16* __restrict__ y) {
  __shared__ u16 xs[12288];                   // [4 mt][6 ks][64 lane][8] bf16
  const int lane = threadIdx.x & 63;
  const int wv = threadIdx.x >> 6;            // 0,1
  // chunked bijective XCD swizzle: 13824 blocks = 8 XCDs x 1728.
  const int fid = (blockIdx.x & 7) * 1728 + (blockIdx.x >> 3);
  const int w = fid / 3, sub = fid - w * 3;   // window, head-pair
  const int h = sub * 2 + wv;                 // this wave's head
  const int bb = w / 576, rem = w - bb * 576;
  const int wy = rem / 24, wx = rem - (rem / 24) * 24;
  const size_t xbase = (size_t)bb * 36864;
  const int g = lane >> 4, li = lane & 15;

  // per-lane pixel for token (mt*16 + li): pix(mt) = pix0 + mt*384
  const int pix0 = (wy * 8 + (li >> 3)) * 192 + wx * 8 + (li & 7);
  const float* xr = x + (xbase + pix0) * 192 + g * 8;
  const u16* wbase = wpack + lane * 8;

  const float scale = 0.17677669529663687f;   // 1/sqrt(32)
  const f32x4 zero4 = {0.f, 0.f, 0.f, 0.f};

  // ---- stage x -> LDS fragments ONCE (2 waves split 24 chunks: 12 each) ----
#pragma unroll
  for (int ci = 0; ci < 12; ++ci) {
    const int c = wv * 12 + ci, mt = c / 6, ks = c - (c / 6) * 6;
    const float* p = xr + mt * 73728 + ks * 32;   // +mt*384 pixels
    float4 f0 = *(const float4*)p;
    float4 f1 = *(const float4*)(p + 4);
    union { bf16x8 v; unsigned u[4]; } o;
    o.u[0] = pkbf(f0.x, f0.y); o.u[1] = pkbf(f0.z, f0.w);
    o.u[2] = pkbf(f1.x, f1.y); o.u[3] = pkbf(f1.z, f1.w);
    *(bf16x8*)(xs + ((mt * 6 + ks) * 64 + lane) * 8) = o.v;
  }
  __syncthreads();

  // ---- pass QK: Q^T, K^T = mfma(W, x_lds)  (64-reg accumulator block) ----
  bf16x8 qf[4], kf[4];
  {
    f32x4 qt[2][4], kt[2][4];
#pragma unroll
    for (int i = 0; i < 2; ++i)
#pragma unroll
      for (int mt = 0; mt < 4; ++mt) { qt[i][mt] = zero4; kt[i][mt] = zero4; }
    __builtin_amdgcn_s_setprio(1);
#pragma unroll
    for (int ks = 0; ks < 6; ++ks) {
      bf16x8 af[4];
#pragma unroll
      for (int mt = 0; mt < 4; ++mt)
        af[mt] = *(const bf16x8*)(xs + ((mt * 6 + ks) * 64 + lane) * 8);
#pragma unroll
      for (int i = 0; i < 2; ++i) {
        bf16x8 wq = *(const bf16x8*)(wbase + ((2 * h + i) * 6 + ks) * 512);
        bf16x8 wk = *(const bf16x8*)(wbase + ((12 + 2 * h + i) * 6 + ks) * 512);
#pragma unroll
        for (int mt = 0; mt < 4; ++mt) {
          qt[i][mt] = MFMA16(wq, af[mt], qt[i][mt]);
          kt[i][mt] = MFMA16(wk, af[mt], kt[i][mt]);
        }
      }
    }
    __builtin_amdgcn_s_setprio(0);
    f32x4 bq0 = *(const f32x4*)(wqkv_b + h * 32 + g * 4);
    f32x4 bq1 = *(const f32x4*)(wqkv_b + h * 32 + 16 + g * 4);
    f32x4 bk0 = *(const f32x4*)(wqkv_b + 192 + h * 32 + g * 4);
    f32x4 bk1 = *(const f32x4*)(wqkv_b + 192 + h * 32 + 16 + g * 4);
#pragma unroll
    for (int mt = 0; mt < 4; ++mt) {
      qf[mt] = xform((qt[0][mt] + bq0) * scale, (qt[1][mt] + bq1) * scale);
      kf[mt] = xform(kt[0][mt] + bk0, kt[1][mt] + bk1);
    }
  }

  // ---- pass V: V = mfma(x_lds, Wv)  (32-reg accumulator block) ----
  bf16x8 vf[2][2];    // [d-tile i][key-chunk ks2] — V^T A-operand
  {
    f32x4 va[4][2];
#pragma unroll
    for (int mt = 0; mt < 4; ++mt) { va[mt][0] = zero4; va[mt][1] = zero4; }
    __builtin_amdgcn_s_setprio(1);
#pragma unroll
    for (int ks = 0; ks < 6; ++ks) {
      bf16x8 af[4];
#pragma unroll
      for (int mt = 0; mt < 4; ++mt)
        af[mt] = *(const bf16x8*)(xs + ((mt * 6 + ks) * 64 + lane) * 8);
      bf16x8 wv0 = *(const bf16x8*)(wbase + ((24 + 2 * h) * 6 + ks) * 512);
      bf16x8 wv1 = *(const bf16x8*)(wbase + ((25 + 2 * h) * 6 + ks) * 512);
#pragma unroll
      for (int mt = 0; mt < 4; ++mt) {
        va[mt][0] = MFMA16(af[mt], wv0, va[mt][0]);
        va[mt][1] = MFMA16(af[mt], wv1, va[mt][1]);
      }
    }
    __builtin_amdgcn_s_setprio(0);
    float bva0 = wqkv_b[384 + h * 32 + li], bva1 = wqkv_b[384 + h * 32 + 16 + li];
#pragma unroll
    for (int i = 0; i < 2; ++i) {
      float bv = i ? bva1 : bva0;
#pragma unroll
      for (int ks2 = 0; ks2 < 2; ++ks2)
        vf[i][ks2] = xform(va[ks2 * 2][i] + bv, va[ks2 * 2 + 1][i] + bv);
    }
  }

  // ---- per-q-tile: S^T = mfma(K,Q,bias), softmax, P-frag, PV, fused store ----
  const float* bfh = biasf + h * 4096 + lane * 4;
  u16* yp = y + (size_t)h * 9437184 + (xbase + pix0) * 32 + g * 8;
#pragma unroll
  for (int nt = 0; nt < 4; ++nt) {
    f32x4 em[4];
    __builtin_amdgcn_s_setprio(1);
#pragma unroll
    for (int mt = 0; mt < 4; ++mt) {
      f32x4 bias_c = *(const f32x4*)(bfh + (nt * 4 + mt) * 256);
      em[mt] = MFMA16(kf[mt], qf[nt], bias_c);   // bias folded into C-operand
    }
    __builtin_amdgcn_s_setprio(0);
    float mx = -1e30f;
#pragma unroll
    for (int mt = 0; mt < 4; ++mt)
      mx = fmaxf(mx, fmaxf(fmaxf(em[mt][0], em[mt][1]), fmaxf(em[mt][2], em[mt][3])));
    mx = pmax16(mx);
    mx = pmax32(mx);
    float s = 0.f;
#pragma unroll
    for (int mt = 0; mt < 4; ++mt)
#pragma unroll
      for (int r = 0; r < 4; ++r) { em[mt][r] = __expf(em[mt][r] - mx); s += em[mt][r]; }
    s = psum16(s);
    s = psum32(s);
    float inv = 1.0f / s;
    f32x4 y0 = zero4, y1 = zero4;   // this q-tile's output only
    __builtin_amdgcn_s_setprio(1);
#pragma unroll
    for (int ks2 = 0; ks2 < 2; ++ks2) {
      bf16x8 pf = xform(em[ks2 * 2] * inv, em[ks2 * 2 + 1] * inv);
      y0 = MFMA16(vf[0][ks2], pf, y0);
      y1 = MFMA16(vf[1][ks2], pf, y1);
    }
    __builtin_amdgcn_s_setprio(0);
    // Y^T -> y-fragment; store HEAD-MAJOR y'[h][b*36864 + pix][32]
    bf16x8 yfr = xform(y0, y1);
    *(bf16x8*)(yp + nt * 12288) = yfr;   // +nt*384 pixels * 32 ch
  }
}

// ---------------- projection GEMM: out = y' @ wp + b, LDS-staged coalesced stores -----
// r25 change (single variable; attn frozen): stage the out-tile in LDS
// (osh[64][196] f32, 196-pad -> 2-way banks = free) and write `out` via a block
// copy in fully contiguous 2 KB runs — the direct version scattered 4x64B
// segments per store instruction (half-line writes). 128-thread blocks, 64 rows
// each, grid 4608; LDS 50176 B -> 3 blocks/CU.
__global__ __launch_bounds__(128, 2) void proj_kernel(
    const u16* __restrict__ y, const u16* __restrict__ wppack,
    const float* __restrict__ wp_b, float* __restrict__ out) {
  __shared__ __align__(16) float osh[64 * 196];
  const int tid = threadIdx.x;
  const int lane = tid & 63, wv = tid >> 6;   // 0,1
  const int g = lane >> 4, li = lane & 15;
  const size_t row0 = (size_t)blockIdx.x * 64 + wv * 32;
  const f32x4 zero4 = {0.f, 0.f, 0.f, 0.f};
  f32x4 acc[2][12];
#pragma unroll
  for (int mt = 0; mt < 2; ++mt)
#pragma unroll
    for (int nt = 0; nt < 12; ++nt) acc[mt][nt] = zero4;
#pragma unroll
  for (int ks = 0; ks < 6; ++ks) {
    bf16x8 af[2];
#pragma unroll
    for (int mt = 0; mt < 2; ++mt)
      af[mt] = *(const bf16x8*)(y + (size_t)ks * 9437184 + (row0 + mt * 16 + li) * 32 + g * 8);
#pragma unroll
    for (int nt = 0; nt < 12; ++nt) {
      bf16x8 bf = *(const bf16x8*)(wppack + (nt * 6 + ks) * 512 + lane * 8);
      acc[0][nt] = MFMA16(af[0], bf, acc[0][nt]);
      acc[1][nt] = MFMA16(af[1], bf, acc[1][nt]);
    }
  }
  // stage to LDS (row-padded 196: g-rows land 16 dwords apart mod 32 -> 2-way, free)
#pragma unroll
  for (int nt = 0; nt < 12; ++nt) {
    float bb = wp_b[nt * 16 + li];
#pragma unroll
    for (int mt = 0; mt < 2; ++mt)
#pragma unroll
      for (int r = 0; r < 4; ++r)
        osh[(wv * 32 + mt * 16 + g * 4 + r) * 196 + nt * 16 + li] = acc[mt][nt][r] + bb;
  }
  __syncthreads();
  // coalesced block copy: 64 rows x 192 floats = 3072 float4, 24 per thread
  const size_t base = (size_t)blockIdx.x * 64 * 192;
#pragma unroll
  for (int i = 0; i < 24; ++i) {
    int idx = i * 128 + tid;
    int row = idx / 48, c4 = idx - row * 48;
    *(float4*)(out + base + row * 192 + c4 * 4) = *(const float4*)(osh + row * 196 + c4 * 4);
  }
}

extern "C" void kernel_launch(void* const* d_in, const int* in_sizes, int n_in,
                              void* d_out, int out_size, void* d_ws, size_t ws_size,
                              hipStream_t stream) {
  (void)in_sizes; (void)n_in; (void)out_size; (void)ws_size;
  const float* x          = (const float*)d_in[0];
  const float* wqkv_w     = (const float*)d_in[1];
  const float* wqkv_b     = (const float*)d_in[2];
  const float* wp_w       = (const float*)d_in[3];
  const float* wp_b       = (const float*)d_in[4];
  const float* bias_table = (const float*)d_in[5];
  float* out = (float*)d_out;
  char* ws = (char*)d_ws;
  u16* wpack   = (u16*)(ws);              // 221184 B
  u16* wppack  = (u16*)(ws + 221184);     //  73728 B
  float* biasf = (float*)(ws + 294912);   //  98304 B
  u16* y       = (u16*)(ws + 393216);     // 113246208 B (head-major: [6][294912][32])

  pack_kernel<<<672, 256, 0, stream>>>(wqkv_w, wp_w, bias_table, wpack, wppack, biasf);
  attn6<<<13824, 128, 0, stream>>>(x, wpack, wqkv_b, biasf, y);
  proj_kernel<<<4608, 128, 0, stream>>>(y, wppack, wp_b, out);
}